// Round 6
// baseline (174.500 us; speedup 1.0000x reference)
//
#include <hip/hip_runtime.h>

// graph_56006373539875: per-edge spring-force scatter.
// R1: global f32 atomics -> 1881us (write-through, 20G atomics/s).
// R2: LDS-privatized redundant scan -> 240us.
// R3: de-gathered scan -> scatter 238us (not gather-bound).
// R4: exact bucketing -> 340us; consume 208us (LDS atomic lane-ops wall).
// R5: i64-packed fixed-point accumulate (1 ds_add_u64 per endpoint) +
//     atomic-free ballot-prefix emit -> 165us; emit=136us, latency-bound
//     at 35% occupancy (grid=256 -> 1 block/CU) with HBM at 17%.
// R6: NBLD 512 (2 blocks/CU -> 32 waves) + unroll-2 emit loop for 2x MLP.

#define NRANGE 8
#define NBLD   512
#define K1T    1024
#define K3T    1024
#define K4T    1024
#define NSLICE 31
#define WPB    (K3T / 64)        // 16 waves per build block
#define NWAVE  (NBLD * WPB)      // 8192 build waves
#define QSCALE 4096.0f           // fixed-point scale 2^12

struct __attribute__((packed, aligned(4))) F3 { float x, y, z; };

// ---------------- K1: per-WAVE per-range endpoint counts (no atomics) -----
__global__ __launch_bounds__(K1T) void count_kernel(
    const int* __restrict__ ea, const int* __restrict__ eb,
    unsigned* __restrict__ counts,           // [NRANGE][NWAVE]
    int n_edges, int chunk, unsigned magic)
{
    const int wid  = blockIdx.x * WPB + ((int)threadIdx.x >> 6);
    const int lane = (int)threadIdx.x & 63;
    const int e0 = wid * chunk;
    const int e1 = min(n_edges, e0 + chunk);

    unsigned c[NRANGE];
#pragma unroll
    for (int j = 0; j < NRANGE; ++j) c[j] = 0;

    for (int e = e0 + lane; e < e1; e += 64) {
        unsigned ra = __umulhi((unsigned)ea[e], magic);
        unsigned rb = __umulhi((unsigned)eb[e], magic);
#pragma unroll
        for (int j = 0; j < NRANGE; ++j)
            c[j] += (ra == (unsigned)j) + (rb == (unsigned)j);
    }
#pragma unroll
    for (int j = 0; j < NRANGE; ++j) {
        unsigned v = c[j];
#pragma unroll
        for (int off = 32; off > 0; off >>= 1) v += __shfl_down(v, off);
        if (lane == 0) counts[j * NWAVE + wid] = v;
    }
}

// ---------------- K2: exclusive prefix over waves, per range (shfl scan) --
__global__ __launch_bounds__(512) void scan_kernel(
    const unsigned* __restrict__ counts,     // [NRANGE][NWAVE]
    unsigned* __restrict__ waveprefix,       // [NRANGE][NWAVE], range-local
    unsigned* __restrict__ rangetotals)      // [NRANGE]
{
    const int j    = (int)threadIdx.x >> 6;  // wave -> range
    const int lane = (int)threadIdx.x & 63;
    unsigned running = 0;
    for (int c = 0; c < NWAVE / 64; ++c) {
        const int idx = c * 64 + lane;
        unsigned v = counts[j * NWAVE + idx];
        const unsigned orig = v;
#pragma unroll
        for (int off = 1; off < 64; off <<= 1) {
            unsigned t = __shfl_up(v, off);
            if (lane >= off) v += t;
        }
        waveprefix[j * NWAVE + idx] = running + v - orig;   // exclusive
        running += __shfl(v, 63);
    }
    if (lane == 0) rangetotals[j] = running;
}

// ---------------- K3: force once, quantize, ballot-prefix slot, emit ------
__global__ __launch_bounds__(K3T) void emit_kernel(
    const float* __restrict__ points, const float* __restrict__ force,
    const int* __restrict__ ea, const int* __restrict__ eb,
    const unsigned* __restrict__ waveprefix, const unsigned* __restrict__ rangetotals,
    ushort4* __restrict__ entries,           // [2*n_edges] {id, qx, qy, qz}
    int n_edges, int chunk, int range, unsigned magic)
{
    const int wid  = blockIdx.x * WPB + ((int)threadIdx.x >> 6);
    const int lane = (int)threadIdx.x & 63;
    const unsigned long long ltmask = (1ULL << lane) - 1ULL;

    unsigned base[NRANGE];
    unsigned run = 0;
#pragma unroll
    for (int j = 0; j < NRANGE; ++j) {
        base[j] = run + waveprefix[j * NWAVE + wid];
        run += rangetotals[j];
    }

    const F3* __restrict__ P = (const F3*)points;
    const int e0 = wid * chunk;
    const int e1 = min(n_edges, e0 + chunk);

#pragma unroll 2
    for (int eBase = e0; eBase < e1; eBase += 64) {
        const int e = eBase + lane;
        const bool valid = e < e1;
        int a = 0, b = 0;
        float f = 0.0f;
        if (valid) { a = ea[e]; b = eb[e]; f = force[e]; }

        F3 pa = P[a];
        F3 pb = P[b];
        float vx = pb.x - pa.x, vy = pb.y - pa.y, vz = pb.z - pa.z;
        float s = -f * rsqrtf(vx * vx + vy * vy + vz * vz + (valid ? 0.0f : 1.0f));

        int qx = __float2int_rn(s * vx * QSCALE);
        int qy = __float2int_rn(s * vy * QSCALE);
        int qz = __float2int_rn(s * vz * QSCALE);
        qx = max(-32767, min(32767, qx));
        qy = max(-32767, min(32767, qy));
        qz = max(-32767, min(32767, qz));

        const unsigned ra  = valid ? __umulhi((unsigned)a, magic) : 0xFFu;
        const unsigned rb2 = valid ? __umulhi((unsigned)b, magic) : 0xFFu;
        const unsigned ida = (unsigned)a - ra  * (unsigned)range;
        const unsigned idb = (unsigned)b - rb2 * (unsigned)range;

        ushort4 entA, entB;
        entA.x = (unsigned short)ida;
        entA.y = (unsigned short)(short)qx;
        entA.z = (unsigned short)(short)qy;
        entA.w = (unsigned short)(short)qz;
        entB.x = (unsigned short)idb;
        entB.y = (unsigned short)(short)(-qx);
        entB.z = (unsigned short)(short)(-qy);
        entB.w = (unsigned short)(short)(-qz);

#pragma unroll
        for (int j = 0; j < NRANGE; ++j) {
            unsigned long long mA = __ballot(ra == (unsigned)j);
            if (ra == (unsigned)j)
                entries[base[j] + __popcll(mA & ltmask)] = entA;
            base[j] += (unsigned)__popcll(mA);
            unsigned long long mB = __ballot(rb2 == (unsigned)j);
            if (rb2 == (unsigned)j)
                entries[base[j] + __popcll(mB & ltmask)] = entB;
            base[j] += (unsigned)__popcll(mB);
        }
    }
}

// ---------------- K4: dense consume, ONE ds_add_u64 per entry -------------
__global__ __launch_bounds__(K4T) void consume_kernel(
    const ushort4* __restrict__ entries, const unsigned* __restrict__ rangetotals,
    float* __restrict__ partial,             // [NSLICE][n_points*3]
    int n_points, int range)
{
    extern __shared__ unsigned long long lds64[];   // [range]
    const int r     = blockIdx.x % NRANGE;
    const int slice = blockIdx.x / NRANGE;

    unsigned base = 0;
    for (int j = 0; j < r; ++j) base += rangetotals[j];
    const unsigned cnt = rangetotals[r];
    const unsigned lo = base + (unsigned)((unsigned long long)cnt * slice / NSLICE);
    const unsigned hi = base + (unsigned)((unsigned long long)cnt * (slice + 1) / NSLICE);

    for (int w = threadIdx.x; w < range; w += K4T) lds64[w] = 0ULL;
    __syncthreads();

    for (unsigned i = lo + threadIdx.x; i < hi; i += K4T) {
        ushort4 q = entries[i];
        long long v = (long long)(short)q.y
                    + ((long long)(short)q.z << 21)
                    + ((long long)(short)q.w << 42);
        atomicAdd(&lds64[q.x], (unsigned long long)v);
    }
    __syncthreads();

    const int total = n_points * 3;
    const int basew = r * range * 3;
    const float inv = 1.0f / QSCALE;
    for (int w = threadIdx.x; w < range; w += K4T) {
        if (r * range + w >= n_points) continue;
        long long T = (long long)lds64[w];
        long long X = ((long long)((unsigned long long)T << 43)) >> 43;
        T = (T - X) >> 21;
        long long Y = ((long long)((unsigned long long)T << 43)) >> 43;
        T = (T - Y) >> 21;
        long long Z = ((long long)((unsigned long long)T << 42)) >> 42;
        float* dst = partial + (size_t)slice * (size_t)total + basew + 3 * w;
        dst[0] = (float)X * inv;
        dst[1] = (float)Y * inv;
        dst[2] = (float)Z * inv;
    }
}

// ---------------- K5: reduce partials + external forces -------------------
__global__ void reduce_kernel(const float* __restrict__ ext,
                              const float* __restrict__ partial,
                              float* __restrict__ out, int n, int nslice)
{
    int i = blockIdx.x * blockDim.x + threadIdx.x;
    if (i >= n) return;
    float s = ext[i];
    for (int c = 0; c < nslice; ++c) s += partial[(size_t)c * (size_t)n + i];
    out[i] = s;
}

// ---------------- fallback: R2 fused redundant scan -----------------------
#define NB_FB 32
#define BLOCK 1024
__global__ __launch_bounds__(BLOCK) void edge_scan_kernel(
    const float* __restrict__ points, const float* __restrict__ force,
    const int* __restrict__ ea, const int* __restrict__ eb,
    float* __restrict__ partial, float* __restrict__ out,
    int n_edges, int n_points, int range, int atomic_mode)
{
    extern __shared__ float lds[];
    const int r = blockIdx.x / NB_FB;
    const int c = blockIdx.x % NB_FB;
    const int node0 = r * range;
    const int nwords = range * 3;
    for (int w = threadIdx.x; w < nwords; w += BLOCK) lds[w] = 0.0f;
    __syncthreads();
    const int chunk = (n_edges + NB_FB - 1) / NB_FB;
    const int e0 = c * chunk, e1 = min(n_edges, e0 + chunk);
    for (int e = e0 + (int)threadIdx.x; e < e1; e += BLOCK) {
        int a = ea[e], b = eb[e];
        int la = a - node0, lb = b - node0;
        bool ha = (unsigned)la < (unsigned)range;
        bool hb = (unsigned)lb < (unsigned)range;
        if (!(ha || hb)) continue;
        float ax = points[3*a], ay = points[3*a+1], az = points[3*a+2];
        float bx = points[3*b], by = points[3*b+1], bz = points[3*b+2];
        float vx = bx-ax, vy = by-ay, vz = bz-az;
        float s = -force[e] * rsqrtf(vx*vx+vy*vy+vz*vz);
        float fx = s*vx, fy = s*vy, fz = s*vz;
        if (ha) { atomicAdd(&lds[la*3+0], fx); atomicAdd(&lds[la*3+1], fy); atomicAdd(&lds[la*3+2], fz); }
        if (hb) { atomicAdd(&lds[lb*3+0], -fx); atomicAdd(&lds[lb*3+1], -fy); atomicAdd(&lds[lb*3+2], -fz); }
    }
    __syncthreads();
    const int basew = node0 * 3;
    const int total = n_points * 3;
    if (atomic_mode) {
        for (int w = threadIdx.x; w < nwords; w += BLOCK)
            if (basew + w < total) atomicAdd(&out[basew + w], lds[w]);
    } else {
        float* dst = partial + (size_t)c * (size_t)total + basew;
        for (int w = threadIdx.x; w < nwords; w += BLOCK)
            if (basew + w < total) dst[w] = lds[w];
    }
}

extern "C" void kernel_launch(void* const* d_in, const int* in_sizes, int n_in,
                              void* d_out, int out_size, void* d_ws, size_t ws_size,
                              hipStream_t stream) {
    const float* points = (const float*)d_in[0];
    const float* ext_f  = (const float*)d_in[1];
    const float* force  = (const float*)d_in[2];
    const int*   ea     = (const int*)d_in[3];
    const int*   eb     = (const int*)d_in[4];
    float* out = (float*)d_out;
    char*  ws  = (char*)d_ws;

    const int n_edges  = in_sizes[2];
    const int total    = out_size;                       // n_points*3
    const int n_points = total / 3;
    const int range    = (n_points + NRANGE - 1) / NRANGE;   // 12500
    const unsigned magic = (unsigned)((0x100000000ULL + range - 1) / (unsigned)range);
    const int chunk = (n_edges + NWAVE - 1) / NWAVE;

    const size_t lds_consume = (size_t)range * sizeof(unsigned long long); // 100KB
    const size_t lds_fb      = (size_t)range * 3 * sizeof(float);          // 150KB

    const size_t entries_b = (size_t)2 * n_edges * sizeof(ushort4);        // 102.4MB
    const size_t partial_b = (size_t)NSLICE * total * sizeof(float);       // 37.2MB
    const size_t cnt_b     = (size_t)NRANGE * NWAVE * sizeof(unsigned);    // 256KB
    // counters alias the partial region (disjoint lifetimes: K1-K3 vs K4-K5)
    const size_t tail_need = (2 * cnt_b + 64 > partial_b) ? (2 * cnt_b + 64) : partial_b;
    const size_t need_new  = entries_b + tail_need;
    const size_t need_fb   = (size_t)NB_FB * total * sizeof(float);        // 38.4MB

    hipFuncSetAttribute((const void*)consume_kernel,
                        hipFuncAttributeMaxDynamicSharedMemorySize, (int)lds_consume);
    hipFuncSetAttribute((const void*)edge_scan_kernel,
                        hipFuncAttributeMaxDynamicSharedMemorySize, (int)lds_fb);

    const int rb = 256;

    if (range <= 0xFFFF && ws_size >= need_new) {
        ushort4*  entries     = (ushort4*)ws;
        float*    partial     = (float*)(ws + entries_b);
        unsigned* counts      = (unsigned*)(ws + entries_b);           // aliases partial
        unsigned* waveprefix  = counts + (size_t)NRANGE * NWAVE;
        unsigned* rangetotals = (unsigned*)(ws + ws_size - 64);        // survives K4/K5

        count_kernel<<<NBLD, K1T, 0, stream>>>(ea, eb, counts, n_edges, chunk, magic);
        scan_kernel<<<1, 512, 0, stream>>>(counts, waveprefix, rangetotals);
        emit_kernel<<<NBLD, K3T, 0, stream>>>(points, force, ea, eb,
                                              waveprefix, rangetotals, entries,
                                              n_edges, chunk, range, magic);
        consume_kernel<<<NRANGE * NSLICE, K4T, lds_consume, stream>>>(
            entries, rangetotals, partial, n_points, range);
        reduce_kernel<<<(total + rb - 1) / rb, rb, 0, stream>>>(
            ext_f, partial, out, total, NSLICE);
    } else if (ws_size >= need_fb) {
        float* partial = (float*)ws;
        edge_scan_kernel<<<NRANGE * NB_FB, BLOCK, lds_fb, stream>>>(
            points, force, ea, eb, partial, out, n_edges, n_points, range, 0);
        reduce_kernel<<<(total + rb - 1) / rb, rb, 0, stream>>>(
            ext_f, partial, out, total, NB_FB);
    } else {
        hipMemcpyAsync(d_out, (const void*)ext_f, (size_t)total * sizeof(float),
                       hipMemcpyDeviceToDevice, stream);
        edge_scan_kernel<<<NRANGE * NB_FB, BLOCK, lds_fb, stream>>>(
            points, force, ea, eb, nullptr, out, n_edges, n_points, range, 1);
    }
}

// Round 7
// 144.012 us; speedup vs baseline: 1.2117x; 1.2117x over previous
//
#include <hip/hip_runtime.h>

// graph_56006373539875: per-edge spring-force scatter.
// R1: global f32 atomics -> 1881us (write-through, 20G atomics/s).
// R2: LDS-privatized redundant scan -> 240us.
// R3: de-gathered scan -> 238us (not gather-bound).
// R4: exact bucketing -> 340us; consume 208us (LDS f32-atomic lane-op wall).
// R5: i64-packed accumulate (1 ds_add_u64/endpoint) + ballot-prefix emit
//     -> 165us; emit=136us.
// R6: 2x occupancy + unroll -> emit EXACTLY unchanged (136us, VALU 24%,
//     HBM 17%) => saturated per-CU VMEM store path: 16 masked scattered
//     8B stores/iter at ~12% lane efficiency.
// R7: LDS ring-buffer staging per (wave,range); ballot slots stay in
//     SGPRs; global stores become dense 64-lane 512B flushes.

#define NRANGE  8
#define NWAVE   4096             // total build waves; chunk = ceil(E/NWAVE)
#define K1T     1024             // count: 16 waves/block -> 256 blocks
#define EWAVES  8                // emit waves/block
#define K3T     (EWAVES * 64)    // 512
#define NBLD3   (NWAVE / EWAVES) // 512 emit blocks
#define RINGCAP 128
#define RINGMSK 127
#define K4T     1024
#define NSLICE  31
#define QSCALE  4096.0f

struct __attribute__((packed, aligned(4))) F3 { float x, y, z; };

// ---------------- K1: per-WAVE per-range endpoint counts (no atomics) -----
__global__ __launch_bounds__(K1T) void count_kernel(
    const int* __restrict__ ea, const int* __restrict__ eb,
    unsigned* __restrict__ counts,           // [NRANGE][NWAVE]
    int n_edges, int chunk, unsigned magic)
{
    const int wid  = blockIdx.x * (K1T / 64) + ((int)threadIdx.x >> 6);
    const int lane = (int)threadIdx.x & 63;
    const int e0 = wid * chunk;
    const int e1 = min(n_edges, e0 + chunk);

    unsigned c[NRANGE];
#pragma unroll
    for (int j = 0; j < NRANGE; ++j) c[j] = 0;

    for (int e = e0 + lane; e < e1; e += 64) {
        unsigned ra = __umulhi((unsigned)ea[e], magic);
        unsigned rb = __umulhi((unsigned)eb[e], magic);
#pragma unroll
        for (int j = 0; j < NRANGE; ++j)
            c[j] += (ra == (unsigned)j) + (rb == (unsigned)j);
    }
#pragma unroll
    for (int j = 0; j < NRANGE; ++j) {
        unsigned v = c[j];
#pragma unroll
        for (int off = 32; off > 0; off >>= 1) v += __shfl_down(v, off);
        if (lane == 0) counts[j * NWAVE + wid] = v;
    }
}

// ---------------- K2: exclusive prefix over waves, per range --------------
__global__ __launch_bounds__(512) void scan_kernel(
    const unsigned* __restrict__ counts,
    unsigned* __restrict__ waveprefix,
    unsigned* __restrict__ rangetotals)
{
    const int j    = (int)threadIdx.x >> 6;
    const int lane = (int)threadIdx.x & 63;
    unsigned running = 0;
    for (int c = 0; c < NWAVE / 64; ++c) {
        const int idx = c * 64 + lane;
        unsigned v = counts[j * NWAVE + idx];
        const unsigned orig = v;
#pragma unroll
        for (int off = 1; off < 64; off <<= 1) {
            unsigned t = __shfl_up(v, off);
            if (lane >= off) v += t;
        }
        waveprefix[j * NWAVE + idx] = running + v - orig;
        running += __shfl(v, 63);
    }
    if (lane == 0) rangetotals[j] = running;
}

// ---------------- K3: emit with LDS ring staging + dense flushes ----------
__global__ __launch_bounds__(K3T) void emit_kernel(
    const float* __restrict__ points, const float* __restrict__ force,
    const int* __restrict__ ea, const int* __restrict__ eb,
    const unsigned* __restrict__ waveprefix, const unsigned* __restrict__ rangetotals,
    uint2* __restrict__ entries,             // [2*n_edges] {id|qx<<16, qy|qz<<16}
    int n_edges, int chunk, int range, unsigned magic)
{
    extern __shared__ uint2 ring[];          // [EWAVES][NRANGE][RINGCAP]
    const int wslot = (int)threadIdx.x >> 6;
    const int wid   = blockIdx.x * EWAVES + wslot;
    const int lane  = (int)threadIdx.x & 63;
    const unsigned long long ltmask = (1ULL << lane) - 1ULL;
    uint2* myring = ring + (size_t)wslot * NRANGE * RINGCAP;

    unsigned segbase[NRANGE], cnt[NRANGE], flushed[NRANGE];
    {
        unsigned run = 0;
#pragma unroll
        for (int j = 0; j < NRANGE; ++j) {
            segbase[j] = run + waveprefix[j * NWAVE + wid];
            run += rangetotals[j];
            cnt[j] = 0;
            flushed[j] = 0;
        }
    }

    const F3* __restrict__ P = (const F3*)points;
    const int e0 = wid * chunk;
    const int e1 = min(n_edges, e0 + chunk);

    for (int eBase = e0; eBase < e1; eBase += 64) {
        const int e = eBase + lane;
        const bool valid = e < e1;
        int a = 0, b = 0;
        float f = 0.0f;
        if (valid) { a = ea[e]; b = eb[e]; f = force[e]; }

        F3 pa = P[a];
        F3 pb = P[b];
        float vx = pb.x - pa.x, vy = pb.y - pa.y, vz = pb.z - pa.z;
        float s = -f * rsqrtf(vx * vx + vy * vy + vz * vz + (valid ? 0.0f : 1.0f));

        int qx = __float2int_rn(s * vx * QSCALE);
        int qy = __float2int_rn(s * vy * QSCALE);
        int qz = __float2int_rn(s * vz * QSCALE);
        qx = max(-32767, min(32767, qx));
        qy = max(-32767, min(32767, qy));
        qz = max(-32767, min(32767, qz));

        const unsigned ra  = valid ? __umulhi((unsigned)a, magic) : 0xFFu;
        const unsigned rb2 = valid ? __umulhi((unsigned)b, magic) : 0xFFu;
        const unsigned ida = (unsigned)a - ra  * (unsigned)range;
        const unsigned idb = (unsigned)b - rb2 * (unsigned)range;

        uint2 entA, entB;
        entA.x = ida | ((unsigned)(unsigned short)(short)qx << 16);
        entA.y = (unsigned)(unsigned short)(short)qy
               | ((unsigned)(unsigned short)(short)qz << 16);
        entB.x = idb | ((unsigned)(unsigned short)(short)(-qx) << 16);
        entB.y = (unsigned)(unsigned short)(short)(-qy)
               | ((unsigned)(unsigned short)(short)(-qz) << 16);

#pragma unroll
        for (int j = 0; j < NRANGE; ++j) {
            // endpoint A append
            unsigned long long mA = __ballot(ra == (unsigned)j);
            if (ra == (unsigned)j)
                myring[j * RINGCAP + ((cnt[j] + __popcll(mA & ltmask)) & RINGMSK)] = entA;
            cnt[j] += (unsigned)__popcll(mA);
            if (cnt[j] - flushed[j] >= 64) {           // wave-uniform
                asm volatile("s_waitcnt lgkmcnt(0)" ::: "memory");
                uint2 v = myring[j * RINGCAP + ((flushed[j] + lane) & RINGMSK)];
                entries[segbase[j] + flushed[j] + lane] = v;
                flushed[j] += 64;
            }
            // endpoint B append
            unsigned long long mB = __ballot(rb2 == (unsigned)j);
            if (rb2 == (unsigned)j)
                myring[j * RINGCAP + ((cnt[j] + __popcll(mB & ltmask)) & RINGMSK)] = entB;
            cnt[j] += (unsigned)__popcll(mB);
            if (cnt[j] - flushed[j] >= 64) {           // wave-uniform
                asm volatile("s_waitcnt lgkmcnt(0)" ::: "memory");
                uint2 v = myring[j * RINGCAP + ((flushed[j] + lane) & RINGMSK)];
                entries[segbase[j] + flushed[j] + lane] = v;
                flushed[j] += 64;
            }
        }
    }

    // drain tails (<64 each)
#pragma unroll
    for (int j = 0; j < NRANGE; ++j) {
        unsigned pend = cnt[j] - flushed[j];
        asm volatile("s_waitcnt lgkmcnt(0)" ::: "memory");
        if ((unsigned)lane < pend) {
            uint2 v = myring[j * RINGCAP + ((flushed[j] + lane) & RINGMSK)];
            entries[segbase[j] + flushed[j] + lane] = v;
        }
    }
}

// ---------------- K4: dense consume, ONE ds_add_u64 per entry -------------
__global__ __launch_bounds__(K4T) void consume_kernel(
    const ushort4* __restrict__ entries, const unsigned* __restrict__ rangetotals,
    float* __restrict__ partial,             // [NSLICE][n_points*3]
    int n_points, int range)
{
    extern __shared__ unsigned long long lds64[];   // [range]
    const int r     = blockIdx.x % NRANGE;
    const int slice = blockIdx.x / NRANGE;

    unsigned base = 0;
    for (int j = 0; j < r; ++j) base += rangetotals[j];
    const unsigned cnt = rangetotals[r];
    const unsigned lo = base + (unsigned)((unsigned long long)cnt * slice / NSLICE);
    const unsigned hi = base + (unsigned)((unsigned long long)cnt * (slice + 1) / NSLICE);

    for (int w = threadIdx.x; w < range; w += K4T) lds64[w] = 0ULL;
    __syncthreads();

    for (unsigned i = lo + threadIdx.x; i < hi; i += K4T) {
        ushort4 q = entries[i];
        long long v = (long long)(short)q.y
                    + ((long long)(short)q.z << 21)
                    + ((long long)(short)q.w << 42);
        atomicAdd(&lds64[q.x], (unsigned long long)v);
    }
    __syncthreads();

    const int total = n_points * 3;
    const int basew = r * range * 3;
    const float inv = 1.0f / QSCALE;
    for (int w = threadIdx.x; w < range; w += K4T) {
        if (r * range + w >= n_points) continue;
        long long T = (long long)lds64[w];
        long long X = ((long long)((unsigned long long)T << 43)) >> 43;
        T = (T - X) >> 21;
        long long Y = ((long long)((unsigned long long)T << 43)) >> 43;
        T = (T - Y) >> 21;
        long long Z = ((long long)((unsigned long long)T << 42)) >> 42;
        float* dst = partial + (size_t)slice * (size_t)total + basew + 3 * w;
        dst[0] = (float)X * inv;
        dst[1] = (float)Y * inv;
        dst[2] = (float)Z * inv;
    }
}

// ---------------- K5: reduce partials + external forces -------------------
__global__ void reduce_kernel(const float* __restrict__ ext,
                              const float* __restrict__ partial,
                              float* __restrict__ out, int n, int nslice)
{
    int i = blockIdx.x * blockDim.x + threadIdx.x;
    if (i >= n) return;
    float s = ext[i];
    for (int c = 0; c < nslice; ++c) s += partial[(size_t)c * (size_t)n + i];
    out[i] = s;
}

// ---------------- fallback: R2 fused redundant scan -----------------------
#define NB_FB 32
#define BLOCK 1024
__global__ __launch_bounds__(BLOCK) void edge_scan_kernel(
    const float* __restrict__ points, const float* __restrict__ force,
    const int* __restrict__ ea, const int* __restrict__ eb,
    float* __restrict__ partial, float* __restrict__ out,
    int n_edges, int n_points, int range, int atomic_mode)
{
    extern __shared__ float lds[];
    const int r = blockIdx.x / NB_FB;
    const int c = blockIdx.x % NB_FB;
    const int node0 = r * range;
    const int nwords = range * 3;
    for (int w = threadIdx.x; w < nwords; w += BLOCK) lds[w] = 0.0f;
    __syncthreads();
    const int chunk = (n_edges + NB_FB - 1) / NB_FB;
    const int e0 = c * chunk, e1 = min(n_edges, e0 + chunk);
    for (int e = e0 + (int)threadIdx.x; e < e1; e += BLOCK) {
        int a = ea[e], b = eb[e];
        int la = a - node0, lb = b - node0;
        bool ha = (unsigned)la < (unsigned)range;
        bool hb = (unsigned)lb < (unsigned)range;
        if (!(ha || hb)) continue;
        float ax = points[3*a], ay = points[3*a+1], az = points[3*a+2];
        float bx = points[3*b], by = points[3*b+1], bz = points[3*b+2];
        float vx = bx-ax, vy = by-ay, vz = bz-az;
        float s = -force[e] * rsqrtf(vx*vx+vy*vy+vz*vz);
        float fx = s*vx, fy = s*vy, fz = s*vz;
        if (ha) { atomicAdd(&lds[la*3+0], fx); atomicAdd(&lds[la*3+1], fy); atomicAdd(&lds[la*3+2], fz); }
        if (hb) { atomicAdd(&lds[lb*3+0], -fx); atomicAdd(&lds[lb*3+1], -fy); atomicAdd(&lds[lb*3+2], -fz); }
    }
    __syncthreads();
    const int basew = node0 * 3;
    const int total = n_points * 3;
    if (atomic_mode) {
        for (int w = threadIdx.x; w < nwords; w += BLOCK)
            if (basew + w < total) atomicAdd(&out[basew + w], lds[w]);
    } else {
        float* dst = partial + (size_t)c * (size_t)total + basew;
        for (int w = threadIdx.x; w < nwords; w += BLOCK)
            if (basew + w < total) dst[w] = lds[w];
    }
}

extern "C" void kernel_launch(void* const* d_in, const int* in_sizes, int n_in,
                              void* d_out, int out_size, void* d_ws, size_t ws_size,
                              hipStream_t stream) {
    const float* points = (const float*)d_in[0];
    const float* ext_f  = (const float*)d_in[1];
    const float* force  = (const float*)d_in[2];
    const int*   ea     = (const int*)d_in[3];
    const int*   eb     = (const int*)d_in[4];
    float* out = (float*)d_out;
    char*  ws  = (char*)d_ws;

    const int n_edges  = in_sizes[2];
    const int total    = out_size;                       // n_points*3
    const int n_points = total / 3;
    const int range    = (n_points + NRANGE - 1) / NRANGE;   // 12500
    const unsigned magic = (unsigned)((0x100000000ULL + range - 1) / (unsigned)range);
    const int chunk = (n_edges + NWAVE - 1) / NWAVE;

    const size_t lds_emit    = (size_t)EWAVES * NRANGE * RINGCAP * sizeof(uint2); // 64KB
    const size_t lds_consume = (size_t)range * sizeof(unsigned long long);        // 100KB
    const size_t lds_fb      = (size_t)range * 3 * sizeof(float);                 // 150KB

    const size_t entries_b = (size_t)2 * n_edges * sizeof(uint2);          // 102.4MB
    const size_t partial_b = (size_t)NSLICE * total * sizeof(float);       // 37.2MB
    const size_t cnt_b     = (size_t)NRANGE * NWAVE * sizeof(unsigned);    // 128KB
    const size_t tail_need = (2 * cnt_b + 64 > partial_b) ? (2 * cnt_b + 64) : partial_b;
    const size_t need_new  = entries_b + tail_need;
    const size_t need_fb   = (size_t)NB_FB * total * sizeof(float);        // 38.4MB

    hipFuncSetAttribute((const void*)emit_kernel,
                        hipFuncAttributeMaxDynamicSharedMemorySize, (int)lds_emit);
    hipFuncSetAttribute((const void*)consume_kernel,
                        hipFuncAttributeMaxDynamicSharedMemorySize, (int)lds_consume);
    hipFuncSetAttribute((const void*)edge_scan_kernel,
                        hipFuncAttributeMaxDynamicSharedMemorySize, (int)lds_fb);

    const int rb = 256;

    if (range <= 0xFFFF && ws_size >= need_new) {
        uint2*    entries     = (uint2*)ws;
        float*    partial     = (float*)(ws + entries_b);
        unsigned* counts      = (unsigned*)(ws + entries_b);           // aliases partial
        unsigned* waveprefix  = counts + (size_t)NRANGE * NWAVE;
        unsigned* rangetotals = (unsigned*)(ws + ws_size - 64);        // survives K4/K5

        count_kernel<<<NWAVE / (K1T / 64), K1T, 0, stream>>>(
            ea, eb, counts, n_edges, chunk, magic);
        scan_kernel<<<1, 512, 0, stream>>>(counts, waveprefix, rangetotals);
        emit_kernel<<<NBLD3, K3T, lds_emit, stream>>>(
            points, force, ea, eb, waveprefix, rangetotals, entries,
            n_edges, chunk, range, magic);
        consume_kernel<<<NRANGE * NSLICE, K4T, lds_consume, stream>>>(
            (const ushort4*)entries, rangetotals, partial, n_points, range);
        reduce_kernel<<<(total + rb - 1) / rb, rb, 0, stream>>>(
            ext_f, partial, out, total, NSLICE);
    } else if (ws_size >= need_fb) {
        float* partial = (float*)ws;
        edge_scan_kernel<<<NRANGE * NB_FB, BLOCK, lds_fb, stream>>>(
            points, force, ea, eb, partial, out, n_edges, n_points, range, 0);
        reduce_kernel<<<(total + rb - 1) / rb, rb, 0, stream>>>(
            ext_f, partial, out, total, NB_FB);
    } else {
        hipMemcpyAsync(d_out, (const void*)ext_f, (size_t)total * sizeof(float),
                       hipMemcpyDeviceToDevice, stream);
        edge_scan_kernel<<<NRANGE * NB_FB, BLOCK, lds_fb, stream>>>(
            points, force, ea, eb, nullptr, out, n_edges, n_points, range, 1);
    }
}

// Round 8
// 138.600 us; speedup vs baseline: 1.2590x; 1.0390x over previous
//
#include <hip/hip_runtime.h>

// graph_56006373539875: per-edge spring-force scatter.
// R1: global f32 atomics -> 1881us (write-through, 20G atomics/s).
// R2: LDS-privatized redundant scan (NR=8, f32 ds_add) -> 240us.
// R3: de-gathered scan -> 238us (not gather-bound).
// R4: exact bucketing -> 340us; f32 consume 208us.
// R5-R7: i64-packed consume + atomic-free emit -> 144us; emit=110us wall.
// Ledger across rounds: ds_add_f32 ~3.2 cyc/lane-op, ds_add_u64 ~0.56
//   (R5/R7 consume = 12.8M lane-ops in ~12us). Integer LDS atomics are
//   ~6x faster => the whole sort/emit pipeline no longer pays for itself.
// R8: FUSED redundant scan with ONE masked ds_add_u64 per hit endpoint.
//   Packed i16 fixed-point fields at bits 0/21/42 (validated since R5);
//   B-side contribution is exactly -v (two's complement). u64 tables
//   allow range=20000 (160KB LDS) -> NR=5 redundancy. blockIdx=r*48+c
//   puts same-chunk blocks 48 apart -> same XCD -> stream re-reads are
//   L2-served (R2 evidence: FETCH 42MB at 8x redundancy). Partials are
//   raw u64 (exact integer reduce), decoded once in the reduce kernel.

#define NR5    5
#define NB5    48
#define SCANT  1024
#define QSCALE 4096.0f

struct __attribute__((packed, aligned(4))) F3 { float x, y, z; };

// ---------------- fused scan: accumulate packed u64 in LDS ----------------
__global__ __launch_bounds__(SCANT) void scan64_kernel(
    const float* __restrict__ points, const float* __restrict__ force,
    const int* __restrict__ ea, const int* __restrict__ eb,
    unsigned long long* __restrict__ partial64,   // [NB5][np_pad]
    int n_edges, int np_pad, int range)
{
    extern __shared__ unsigned long long lds64[];   // [range]
    const int r = blockIdx.x / NB5;
    const int c = blockIdx.x % NB5;
    const int node0 = r * range;

    for (int w = threadIdx.x; w < range; w += SCANT) lds64[w] = 0ULL;
    __syncthreads();

    const F3* __restrict__ P = (const F3*)points;
    const int chunk = (n_edges + NB5 - 1) / NB5;
    const int e0 = c * chunk;
    const int e1 = min(n_edges, e0 + chunk);

    for (int e = e0 + (int)threadIdx.x; e < e1; e += SCANT) {
        int a = ea[e];
        int b = eb[e];
        int la = a - node0;
        int lb = b - node0;
        bool ha = (unsigned)la < (unsigned)range;
        bool hb = (unsigned)lb < (unsigned)range;
        if (ha || hb) {
            float f = force[e];
            F3 pa = P[a];
            F3 pb = P[b];
            float vx = pb.x - pa.x, vy = pb.y - pa.y, vz = pb.z - pa.z;
            float s = -f * rsqrtf(vx * vx + vy * vy + vz * vz);

            int qx = __float2int_rn(s * vx * QSCALE);
            int qy = __float2int_rn(s * vy * QSCALE);
            int qz = __float2int_rn(s * vz * QSCALE);
            qx = max(-32767, min(32767, qx));
            qy = max(-32767, min(32767, qy));
            qz = max(-32767, min(32767, qz));

            long long v = (long long)qx
                        + ((long long)qy << 21)
                        + ((long long)qz << 42);
            if (ha) atomicAdd(&lds64[la], (unsigned long long)v);
            if (hb) atomicAdd(&lds64[lb], (unsigned long long)(-v));
        }
    }
    __syncthreads();

    // flush raw u64 partial segment (coalesced 8B/lane)
    unsigned long long* dst = partial64 + (size_t)c * (size_t)np_pad + node0;
    for (int w = threadIdx.x; w < range; w += SCANT) dst[w] = lds64[w];
}

// ---------------- reduce: u64 sum (exact) -> decode -> + ext --------------
__global__ void reduce64_kernel(const float* __restrict__ ext,
                                const unsigned long long* __restrict__ partial64,
                                float* __restrict__ out, int n_points, int np_pad)
{
    int i = blockIdx.x * blockDim.x + threadIdx.x;
    if (i >= n_points) return;
    unsigned long long t = 0ULL;
#pragma unroll
    for (int c = 0; c < NB5; ++c)
        t += partial64[(size_t)c * (size_t)np_pad + i];

    long long T = (long long)t;
    long long X = ((long long)((unsigned long long)T << 43)) >> 43;
    T = (T - X) >> 21;
    long long Y = ((long long)((unsigned long long)T << 43)) >> 43;
    T = (T - Y) >> 21;
    long long Z = ((long long)((unsigned long long)T << 42)) >> 42;

    const float inv = 1.0f / QSCALE;
    out[3 * i + 0] = ext[3 * i + 0] + (float)X * inv;
    out[3 * i + 1] = ext[3 * i + 1] + (float)Y * inv;
    out[3 * i + 2] = ext[3 * i + 2] + (float)Z * inv;
}

// ---------------- fallback: fused scan with direct atomic flush -----------
#define NR_FB 8
#define NB_FB 32
#define BLOCK 1024
__global__ __launch_bounds__(BLOCK) void edge_scan_kernel(
    const float* __restrict__ points, const float* __restrict__ force,
    const int* __restrict__ ea, const int* __restrict__ eb,
    float* __restrict__ out,
    int n_edges, int n_points, int range)
{
    extern __shared__ float lds[];
    const int r = blockIdx.x / NB_FB;
    const int c = blockIdx.x % NB_FB;
    const int node0 = r * range;
    const int nwords = range * 3;
    for (int w = threadIdx.x; w < nwords; w += BLOCK) lds[w] = 0.0f;
    __syncthreads();
    const int chunk = (n_edges + NB_FB - 1) / NB_FB;
    const int e0 = c * chunk, e1 = min(n_edges, e0 + chunk);
    for (int e = e0 + (int)threadIdx.x; e < e1; e += BLOCK) {
        int a = ea[e], b = eb[e];
        int la = a - node0, lb = b - node0;
        bool ha = (unsigned)la < (unsigned)range;
        bool hb = (unsigned)lb < (unsigned)range;
        if (!(ha || hb)) continue;
        float ax = points[3*a], ay = points[3*a+1], az = points[3*a+2];
        float bx = points[3*b], by = points[3*b+1], bz = points[3*b+2];
        float vx = bx-ax, vy = by-ay, vz = bz-az;
        float s = -force[e] * rsqrtf(vx*vx+vy*vy+vz*vz);
        float fx = s*vx, fy = s*vy, fz = s*vz;
        if (ha) { atomicAdd(&lds[la*3+0], fx); atomicAdd(&lds[la*3+1], fy); atomicAdd(&lds[la*3+2], fz); }
        if (hb) { atomicAdd(&lds[lb*3+0], -fx); atomicAdd(&lds[lb*3+1], -fy); atomicAdd(&lds[lb*3+2], -fz); }
    }
    __syncthreads();
    const int basew = node0 * 3;
    const int total = n_points * 3;
    for (int w = threadIdx.x; w < nwords; w += BLOCK)
        if (basew + w < total) atomicAdd(&out[basew + w], lds[w]);
}

extern "C" void kernel_launch(void* const* d_in, const int* in_sizes, int n_in,
                              void* d_out, int out_size, void* d_ws, size_t ws_size,
                              hipStream_t stream) {
    const float* points = (const float*)d_in[0];
    const float* ext_f  = (const float*)d_in[1];
    const float* force  = (const float*)d_in[2];
    const int*   ea     = (const int*)d_in[3];
    const int*   eb     = (const int*)d_in[4];
    float* out = (float*)d_out;
    char*  ws  = (char*)d_ws;

    const int n_edges  = in_sizes[2];
    const int total    = out_size;                       // n_points*3
    const int n_points = total / 3;

    // fused-u64 path geometry
    const int range5  = (n_points + NR5 - 1) / NR5;      // 20000
    const int np_pad  = range5 * NR5;
    const size_t lds_scan = (size_t)range5 * sizeof(unsigned long long); // 160000
    const size_t part_b   = (size_t)NB5 * (size_t)np_pad * sizeof(unsigned long long); // 38.4MB

    // fallback geometry
    const int range_fb = (n_points + NR_FB - 1) / NR_FB;  // 12500
    const size_t lds_fb = (size_t)range_fb * 3 * sizeof(float);          // 150KB

    hipFuncSetAttribute((const void*)scan64_kernel,
                        hipFuncAttributeMaxDynamicSharedMemorySize, (int)lds_scan);
    hipFuncSetAttribute((const void*)edge_scan_kernel,
                        hipFuncAttributeMaxDynamicSharedMemorySize, (int)lds_fb);

    if (lds_scan <= 160 * 1024 && ws_size >= part_b) {
        unsigned long long* partial64 = (unsigned long long*)ws;
        scan64_kernel<<<NR5 * NB5, SCANT, lds_scan, stream>>>(
            points, force, ea, eb, partial64, n_edges, np_pad, range5);
        const int rb = 256;
        reduce64_kernel<<<(n_points + rb - 1) / rb, rb, 0, stream>>>(
            ext_f, partial64, out, n_points, np_pad);
    } else {
        hipMemcpyAsync(d_out, (const void*)ext_f, (size_t)total * sizeof(float),
                       hipMemcpyDeviceToDevice, stream);
        edge_scan_kernel<<<NR_FB * NB_FB, BLOCK, lds_fb, stream>>>(
            points, force, ea, eb, out, n_edges, n_points, range_fb);
    }
}

// Round 9
// 136.185 us; speedup vs baseline: 1.2813x; 1.0177x over previous
//
#include <hip/hip_runtime.h>

// graph_56006373539875: per-edge spring-force scatter.
// R1: global f32 atomics -> 1881us. R2: LDS f32 redundant scan -> 240us.
// R3: de-gathered scan -> 238us. R4: bucketing, f32 consume 208us.
// R5-R7: i64-packed consume (ds_add_u64 ~0.56cyc/lane-op) + sort emit
//        -> 144us, emit-bound (110us).
// R8: fused scan, 1 ds_add_u64/hit, NR=5 (160KB LDS) -> 138us; scan is
//     latency-bound: 16 waves/CU (LDS cap), ~150cyc/wave-exam vs ~60 issue,
//     VALU 23%, HBM 5%.
// R9: same structure + in-wave MLP: 4 edges/thread/iter via int4/float4
//     stream loads; BRANCHLESS gathers (miss lanes -> P[0], same-line
//     merge in TA) issued 8-deep before any math; only ds_adds masked.

#define NR5    5
#define NB5    48
#define SCANT  1024
#define QSCALE 4096.0f

struct __attribute__((packed, aligned(4))) F3 { float x, y, z; };

// ---------------- fused scan: accumulate packed u64 in LDS ----------------
__global__ __launch_bounds__(SCANT) void scan64_kernel(
    const float* __restrict__ points, const float* __restrict__ force,
    const int* __restrict__ ea, const int* __restrict__ eb,
    unsigned long long* __restrict__ partial64,   // [NB5][np_pad]
    int n_edges, int np_pad, int range, int chunk)
{
    extern __shared__ unsigned long long lds64[];   // [range]
    const int r = blockIdx.x / NB5;
    const int c = blockIdx.x % NB5;
    const int node0 = r * range;

    for (int w = threadIdx.x; w < range; w += SCANT) lds64[w] = 0ULL;
    __syncthreads();

    const F3* __restrict__ P = (const F3*)points;
    const int e0 = min(n_edges, c * chunk);
    const int e1 = min(n_edges, e0 + chunk);
    const int nvec = (e1 - e0) & ~3;                // multiple of 4

    const int4*   ea4 = (const int4*)(ea + e0);     // e0 % 4 == 0 -> 16B aligned
    const int4*   eb4 = (const int4*)(eb + e0);
    const float4* ff4 = (const float4*)(force + e0);

    for (int g = (int)threadIdx.x; g < (nvec >> 2); g += SCANT) {
        int4   a4 = ea4[g];
        int4   b4 = eb4[g];
        float4 f4 = ff4[g];

        // ---- stage 1: masks + branchless gather issue (8 loads in flight)
        int la0 = a4.x - node0, lb0 = b4.x - node0;
        int la1 = a4.y - node0, lb1 = b4.y - node0;
        int la2 = a4.z - node0, lb2 = b4.z - node0;
        int la3 = a4.w - node0, lb3 = b4.w - node0;
        bool ha0 = (unsigned)la0 < (unsigned)range, hb0 = (unsigned)lb0 < (unsigned)range;
        bool ha1 = (unsigned)la1 < (unsigned)range, hb1 = (unsigned)lb1 < (unsigned)range;
        bool ha2 = (unsigned)la2 < (unsigned)range, hb2 = (unsigned)lb2 < (unsigned)range;
        bool ha3 = (unsigned)la3 < (unsigned)range, hb3 = (unsigned)lb3 < (unsigned)range;
        bool h0 = ha0 || hb0, h1 = ha1 || hb1, h2 = ha2 || hb2, h3 = ha3 || hb3;

        F3 pa0 = P[h0 ? a4.x : 0];  F3 pb0 = P[h0 ? b4.x : 0];
        F3 pa1 = P[h1 ? a4.y : 0];  F3 pb1 = P[h1 ? b4.y : 0];
        F3 pa2 = P[h2 ? a4.z : 0];  F3 pb2 = P[h2 ? b4.z : 0];
        F3 pa3 = P[h3 ? a4.w : 0];  F3 pb3 = P[h3 ? b4.w : 0];

        // ---- stage 2: math + masked ds_add_u64
#define PROC(pa, pb, fsc, hit, ha, hb, la, lb)                                   \
        {                                                                        \
            float vx = pb.x - pa.x, vy = pb.y - pa.y, vz = pb.z - pa.z;          \
            float n2 = vx * vx + vy * vy + vz * vz;                              \
            float s  = -(fsc) * rsqrtf((hit) ? n2 : 1.0f);                       \
            int qx = __float2int_rn(s * vx * QSCALE);                            \
            int qy = __float2int_rn(s * vy * QSCALE);                            \
            int qz = __float2int_rn(s * vz * QSCALE);                            \
            qx = max(-32767, min(32767, qx));                                    \
            qy = max(-32767, min(32767, qy));                                    \
            qz = max(-32767, min(32767, qz));                                    \
            long long v = (long long)qx + ((long long)qy << 21)                  \
                        + ((long long)qz << 42);                                 \
            if (ha) atomicAdd(&lds64[la], (unsigned long long)v);                \
            if (hb) atomicAdd(&lds64[lb], (unsigned long long)(-v));             \
        }

        PROC(pa0, pb0, f4.x, h0, ha0, hb0, la0, lb0)
        PROC(pa1, pb1, f4.y, h1, ha1, hb1, la1, lb1)
        PROC(pa2, pb2, f4.z, h2, ha2, hb2, la2, lb2)
        PROC(pa3, pb3, f4.w, h3, ha3, hb3, la3, lb3)
#undef PROC
    }

    // scalar tail (last chunk only, <4 edges)
    for (int e = e0 + nvec + (int)threadIdx.x; e < e1; e += SCANT) {
        int a = ea[e], b = eb[e];
        int la = a - node0, lb = b - node0;
        bool ha = (unsigned)la < (unsigned)range;
        bool hb = (unsigned)lb < (unsigned)range;
        if (ha || hb) {
            F3 pa = P[a], pb = P[b];
            float vx = pb.x - pa.x, vy = pb.y - pa.y, vz = pb.z - pa.z;
            float s = -force[e] * rsqrtf(vx * vx + vy * vy + vz * vz);
            int qx = __float2int_rn(s * vx * QSCALE);
            int qy = __float2int_rn(s * vy * QSCALE);
            int qz = __float2int_rn(s * vz * QSCALE);
            qx = max(-32767, min(32767, qx));
            qy = max(-32767, min(32767, qy));
            qz = max(-32767, min(32767, qz));
            long long v = (long long)qx + ((long long)qy << 21) + ((long long)qz << 42);
            if (ha) atomicAdd(&lds64[la], (unsigned long long)v);
            if (hb) atomicAdd(&lds64[lb], (unsigned long long)(-v));
        }
    }
    __syncthreads();

    // flush raw u64 partial segment (coalesced 8B/lane)
    unsigned long long* dst = partial64 + (size_t)c * (size_t)np_pad + node0;
    for (int w = threadIdx.x; w < range; w += SCANT) dst[w] = lds64[w];
}

// ---------------- reduce: u64 sum (exact) -> decode -> + ext --------------
__global__ void reduce64_kernel(const float* __restrict__ ext,
                                const unsigned long long* __restrict__ partial64,
                                float* __restrict__ out, int n_points, int np_pad)
{
    int i = blockIdx.x * blockDim.x + threadIdx.x;
    if (i >= n_points) return;
    unsigned long long t = 0ULL;
#pragma unroll
    for (int c = 0; c < NB5; ++c)
        t += partial64[(size_t)c * (size_t)np_pad + i];

    long long T = (long long)t;
    long long X = ((long long)((unsigned long long)T << 43)) >> 43;
    T = (T - X) >> 21;
    long long Y = ((long long)((unsigned long long)T << 43)) >> 43;
    T = (T - Y) >> 21;
    long long Z = ((long long)((unsigned long long)T << 42)) >> 42;

    const float inv = 1.0f / QSCALE;
    out[3 * i + 0] = ext[3 * i + 0] + (float)X * inv;
    out[3 * i + 1] = ext[3 * i + 1] + (float)Y * inv;
    out[3 * i + 2] = ext[3 * i + 2] + (float)Z * inv;
}

// ---------------- fallback: fused scan with direct atomic flush -----------
#define NR_FB 8
#define NB_FB 32
#define BLOCK 1024
__global__ __launch_bounds__(BLOCK) void edge_scan_kernel(
    const float* __restrict__ points, const float* __restrict__ force,
    const int* __restrict__ ea, const int* __restrict__ eb,
    float* __restrict__ out,
    int n_edges, int n_points, int range)
{
    extern __shared__ float lds[];
    const int r = blockIdx.x / NB_FB;
    const int c = blockIdx.x % NB_FB;
    const int node0 = r * range;
    const int nwords = range * 3;
    for (int w = threadIdx.x; w < nwords; w += BLOCK) lds[w] = 0.0f;
    __syncthreads();
    const int chunk = (n_edges + NB_FB - 1) / NB_FB;
    const int e0 = c * chunk, e1 = min(n_edges, e0 + chunk);
    for (int e = e0 + (int)threadIdx.x; e < e1; e += BLOCK) {
        int a = ea[e], b = eb[e];
        int la = a - node0, lb = b - node0;
        bool ha = (unsigned)la < (unsigned)range;
        bool hb = (unsigned)lb < (unsigned)range;
        if (!(ha || hb)) continue;
        float ax = points[3*a], ay = points[3*a+1], az = points[3*a+2];
        float bx = points[3*b], by = points[3*b+1], bz = points[3*b+2];
        float vx = bx-ax, vy = by-ay, vz = bz-az;
        float s = -force[e] * rsqrtf(vx*vx+vy*vy+vz*vz);
        float fx = s*vx, fy = s*vy, fz = s*vz;
        if (ha) { atomicAdd(&lds[la*3+0], fx); atomicAdd(&lds[la*3+1], fy); atomicAdd(&lds[la*3+2], fz); }
        if (hb) { atomicAdd(&lds[lb*3+0], -fx); atomicAdd(&lds[lb*3+1], -fy); atomicAdd(&lds[lb*3+2], -fz); }
    }
    __syncthreads();
    const int basew = node0 * 3;
    const int total = n_points * 3;
    for (int w = threadIdx.x; w < nwords; w += BLOCK)
        if (basew + w < total) atomicAdd(&out[basew + w], lds[w]);
}

extern "C" void kernel_launch(void* const* d_in, const int* in_sizes, int n_in,
                              void* d_out, int out_size, void* d_ws, size_t ws_size,
                              hipStream_t stream) {
    const float* points = (const float*)d_in[0];
    const float* ext_f  = (const float*)d_in[1];
    const float* force  = (const float*)d_in[2];
    const int*   ea     = (const int*)d_in[3];
    const int*   eb     = (const int*)d_in[4];
    float* out = (float*)d_out;
    char*  ws  = (char*)d_ws;

    const int n_edges  = in_sizes[2];
    const int total    = out_size;                       // n_points*3
    const int n_points = total / 3;

    // fused-u64 path geometry
    const int range5  = (n_points + NR5 - 1) / NR5;      // 20000
    const int np_pad  = range5 * NR5;
    const int chunk   = (((n_edges + NB5 - 1) / NB5) + 3) & ~3;  // x4 for int4
    const size_t lds_scan = (size_t)range5 * sizeof(unsigned long long); // 160000
    const size_t part_b   = (size_t)NB5 * (size_t)np_pad * sizeof(unsigned long long); // 38.4MB

    // fallback geometry
    const int range_fb = (n_points + NR_FB - 1) / NR_FB;  // 12500
    const size_t lds_fb = (size_t)range_fb * 3 * sizeof(float);          // 150KB

    hipFuncSetAttribute((const void*)scan64_kernel,
                        hipFuncAttributeMaxDynamicSharedMemorySize, (int)lds_scan);
    hipFuncSetAttribute((const void*)edge_scan_kernel,
                        hipFuncAttributeMaxDynamicSharedMemorySize, (int)lds_fb);

    if (lds_scan <= 160 * 1024 && ws_size >= part_b) {
        unsigned long long* partial64 = (unsigned long long*)ws;
        scan64_kernel<<<NR5 * NB5, SCANT, lds_scan, stream>>>(
            points, force, ea, eb, partial64, n_edges, np_pad, range5, chunk);
        const int rb = 256;
        reduce64_kernel<<<(n_points + rb - 1) / rb, rb, 0, stream>>>(
            ext_f, partial64, out, n_points, np_pad);
    } else {
        hipMemcpyAsync(d_out, (const void*)ext_f, (size_t)total * sizeof(float),
                       hipMemcpyDeviceToDevice, stream);
        edge_scan_kernel<<<NR_FB * NB_FB, BLOCK, lds_fb, stream>>>(
            points, force, ea, eb, out, n_edges, n_points, range_fb);
    }
}

// Round 10
// 135.672 us; speedup vs baseline: 1.2862x; 1.0038x over previous
//
#include <hip/hip_runtime.h>

// graph_56006373539875: per-edge spring-force scatter.
// R1: global f32 atomics -> 1881us. R2: LDS f32 redundant scan -> 240us.
// R3: de-gathered scan -> 238us. R4: bucket+f32 consume -> 340us.
// R5-R7: i64-packed consume + ballot/ring emit -> 144us (emit 110us wall:
//        serial 16-round ballot machinery).
// R8-R9: fused u64 scan (NR=5) -> 136-138us; latency-bound at 16 waves/CU
//        (LDS cap), per-exam floor ~2.5cyc x 32M exams. Dead end.
// R10: sort pipeline with LEAN emit: per-wave LDS u32 counters allocate
//      slots (1 atomicAdd/endpoint, ~0.5cyc/lane-op integer LDS) ->
//      one all-lane 8B store per endpoint. No ballot rounds, no ring,
//      no redundancy, tiny LDS -> full occupancy. Consume = dense u64
//      (proven ~0.56cyc/lane-op), raw u64 partials, exact int reduce.

#define NR5    5
#define NWAVE  4096
#define K1T    1024              // count: 16 waves/block -> 256 blocks
#define EWAVES 8                 // emit: 8 waves/block -> 512 blocks
#define K3T    (EWAVES * 64)
#define NBLD3  (NWAVE / EWAVES)
#define K4T    1024
#define NSLICE 44                // consume slices/range -> grid 220
#define QSCALE 4096.0f

struct __attribute__((packed, aligned(4))) F3 { float x, y, z; };

// ---------------- K1: per-WAVE per-range endpoint counts ------------------
__global__ __launch_bounds__(K1T) void count_kernel(
    const int* __restrict__ ea, const int* __restrict__ eb,
    unsigned* __restrict__ counts,           // [NR5][NWAVE]
    int n_edges, int chunk, unsigned magic)
{
    const int wid  = blockIdx.x * (K1T / 64) + ((int)threadIdx.x >> 6);
    const int lane = (int)threadIdx.x & 63;
    const int e0 = min(n_edges, wid * chunk);
    const int e1 = min(n_edges, e0 + chunk);
    const int nvec = (e1 - e0) & ~3;

    unsigned c[NR5];
#pragma unroll
    for (int j = 0; j < NR5; ++j) c[j] = 0;

    const int4* ea4 = (const int4*)(ea + e0);
    const int4* eb4 = (const int4*)(eb + e0);
    for (int g = lane; g < (nvec >> 2); g += 64) {
        int4 a4 = ea4[g];
        int4 b4 = eb4[g];
        unsigned r0 = __umulhi((unsigned)a4.x, magic), s0 = __umulhi((unsigned)b4.x, magic);
        unsigned r1 = __umulhi((unsigned)a4.y, magic), s1 = __umulhi((unsigned)b4.y, magic);
        unsigned r2 = __umulhi((unsigned)a4.z, magic), s2 = __umulhi((unsigned)b4.z, magic);
        unsigned r3 = __umulhi((unsigned)a4.w, magic), s3 = __umulhi((unsigned)b4.w, magic);
#pragma unroll
        for (int j = 0; j < NR5; ++j)
            c[j] += (r0 == (unsigned)j) + (s0 == (unsigned)j)
                  + (r1 == (unsigned)j) + (s1 == (unsigned)j)
                  + (r2 == (unsigned)j) + (s2 == (unsigned)j)
                  + (r3 == (unsigned)j) + (s3 == (unsigned)j);
    }
    for (int e = e0 + nvec + lane; e < e1; e += 64) {
        unsigned ra = __umulhi((unsigned)ea[e], magic);
        unsigned rb = __umulhi((unsigned)eb[e], magic);
#pragma unroll
        for (int j = 0; j < NR5; ++j)
            c[j] += (ra == (unsigned)j) + (rb == (unsigned)j);
    }
#pragma unroll
    for (int j = 0; j < NR5; ++j) {
        unsigned v = c[j];
#pragma unroll
        for (int off = 32; off > 0; off >>= 1) v += __shfl_down(v, off);
        if (lane == 0) counts[j * NWAVE + wid] = v;
    }
}

// ---------------- K2: exclusive prefix over waves, per range --------------
__global__ __launch_bounds__(NR5 * 64) void scan_kernel(
    const unsigned* __restrict__ counts,
    unsigned* __restrict__ waveprefix,
    unsigned* __restrict__ rangetotals)
{
    const int j    = (int)threadIdx.x >> 6;
    const int lane = (int)threadIdx.x & 63;
    unsigned running = 0;
    for (int c = 0; c < NWAVE / 64; ++c) {
        const int idx = c * 64 + lane;
        unsigned v = counts[j * NWAVE + idx];
        const unsigned orig = v;
#pragma unroll
        for (int off = 1; off < 64; off <<= 1) {
            unsigned t = __shfl_up(v, off);
            if (lane >= off) v += t;
        }
        waveprefix[j * NWAVE + idx] = running + v - orig;
        running += __shfl(v, 63);
    }
    if (lane == 0) rangetotals[j] = running;
}

// ---------------- K3: emit via LDS-counter slot alloc + direct store ------
__global__ __launch_bounds__(K3T) void emit_kernel(
    const float* __restrict__ points, const float* __restrict__ force,
    const int* __restrict__ ea, const int* __restrict__ eb,
    const unsigned* __restrict__ waveprefix, const unsigned* __restrict__ rangetotals,
    uint2* __restrict__ entries,             // [2*n_edges] {id|qx<<16, qy|qz<<16}
    int n_edges, int chunk, int range, unsigned magic)
{
    __shared__ unsigned cnt[EWAVES][NR5];
    const int wslot = (int)threadIdx.x >> 6;
    const int lane  = (int)threadIdx.x & 63;
    const int wid   = blockIdx.x * EWAVES + wslot;

    if (lane < NR5) {
        unsigned base = 0;
        for (int k = 0; k < lane; ++k) base += rangetotals[k];
        cnt[wslot][lane] = base + waveprefix[lane * NWAVE + wid];
    }
    __syncthreads();

    const F3* __restrict__ P = (const F3*)points;
    const int e0 = min(n_edges, wid * chunk);
    const int e1 = min(n_edges, e0 + chunk);
    const int nvec = (e1 - e0) & ~3;

    const int4*   ea4 = (const int4*)(ea + e0);
    const int4*   eb4 = (const int4*)(eb + e0);
    const float4* ff4 = (const float4*)(force + e0);

#define PROCE(pa, pb, fsc, aa, bb)                                               \
    {                                                                            \
        float vx = pb.x - pa.x, vy = pb.y - pa.y, vz = pb.z - pa.z;              \
        float s  = -(fsc) * rsqrtf(vx * vx + vy * vy + vz * vz);                 \
        int qx = __float2int_rn(s * vx * QSCALE);                                \
        int qy = __float2int_rn(s * vy * QSCALE);                                \
        int qz = __float2int_rn(s * vz * QSCALE);                                \
        qx = max(-32767, min(32767, qx));                                        \
        qy = max(-32767, min(32767, qy));                                        \
        qz = max(-32767, min(32767, qz));                                        \
        unsigned ra = __umulhi((unsigned)(aa), magic);                           \
        unsigned rb = __umulhi((unsigned)(bb), magic);                           \
        unsigned ida = (unsigned)(aa) - ra * (unsigned)range;                    \
        unsigned idb = (unsigned)(bb) - rb * (unsigned)range;                    \
        uint2 entA, entB;                                                        \
        entA.x = ida | ((unsigned)(unsigned short)(short)qx << 16);              \
        entA.y = (unsigned)(unsigned short)(short)qy                             \
               | ((unsigned)(unsigned short)(short)qz << 16);                    \
        entB.x = idb | ((unsigned)(unsigned short)(short)(-qx) << 16);           \
        entB.y = (unsigned)(unsigned short)(short)(-qy)                          \
               | ((unsigned)(unsigned short)(short)(-qz) << 16);                 \
        unsigned sA = atomicAdd(&cnt[wslot][ra], 1u);                            \
        entries[sA] = entA;                                                      \
        unsigned sB = atomicAdd(&cnt[wslot][rb], 1u);                            \
        entries[sB] = entB;                                                      \
    }

    for (int g = lane; g < (nvec >> 2); g += 64) {
        int4   a4 = ea4[g];
        int4   b4 = eb4[g];
        float4 f4 = ff4[g];
        // issue all 8 gathers before any math (MLP)
        F3 pa0 = P[a4.x]; F3 pb0 = P[b4.x];
        F3 pa1 = P[a4.y]; F3 pb1 = P[b4.y];
        F3 pa2 = P[a4.z]; F3 pb2 = P[b4.z];
        F3 pa3 = P[a4.w]; F3 pb3 = P[b4.w];
        PROCE(pa0, pb0, f4.x, a4.x, b4.x)
        PROCE(pa1, pb1, f4.y, a4.y, b4.y)
        PROCE(pa2, pb2, f4.z, a4.z, b4.z)
        PROCE(pa3, pb3, f4.w, a4.w, b4.w)
    }
    for (int e = e0 + nvec + lane; e < e1; e += 64) {
        int a = ea[e], b = eb[e];
        F3 pa = P[a], pb = P[b];
        float f = force[e];
        PROCE(pa, pb, f, a, b)
    }
#undef PROCE
}

// ---------------- K4: dense consume, ONE ds_add_u64 per entry -------------
__global__ __launch_bounds__(K4T) void consume_kernel(
    const ushort4* __restrict__ entries, const unsigned* __restrict__ rangetotals,
    unsigned long long* __restrict__ partial64,   // [NSLICE][np_pad]
    int np_pad, int range)
{
    extern __shared__ unsigned long long lds64[];   // [range]
    const int r     = blockIdx.x % NR5;
    const int slice = blockIdx.x / NR5;

    unsigned base = 0;
    for (int j = 0; j < r; ++j) base += rangetotals[j];
    const unsigned cnt = rangetotals[r];
    const unsigned lo = base + (unsigned)((unsigned long long)cnt * slice / NSLICE);
    const unsigned hi = base + (unsigned)((unsigned long long)cnt * (slice + 1) / NSLICE);

    for (int w = threadIdx.x; w < range; w += K4T) lds64[w] = 0ULL;
    __syncthreads();

    for (unsigned i = lo + threadIdx.x; i < hi; i += K4T) {
        ushort4 q = entries[i];
        long long v = (long long)(short)q.y
                    + ((long long)(short)q.z << 21)
                    + ((long long)(short)q.w << 42);
        atomicAdd(&lds64[q.x], (unsigned long long)v);
    }
    __syncthreads();

    unsigned long long* dst = partial64 + (size_t)slice * (size_t)np_pad
                            + (size_t)r * (size_t)range;
    for (int w = threadIdx.x; w < range; w += K4T) dst[w] = lds64[w];
}

// ---------------- K5: exact u64 reduce -> decode -> + ext -----------------
__global__ void reduce64_kernel(const float* __restrict__ ext,
                                const unsigned long long* __restrict__ partial64,
                                float* __restrict__ out, int n_points, int np_pad)
{
    int i = blockIdx.x * blockDim.x + threadIdx.x;
    if (i >= n_points) return;
    unsigned long long t = 0ULL;
#pragma unroll 4
    for (int c = 0; c < NSLICE; ++c)
        t += partial64[(size_t)c * (size_t)np_pad + i];

    long long T = (long long)t;
    long long X = ((long long)((unsigned long long)T << 43)) >> 43;
    T = (T - X) >> 21;
    long long Y = ((long long)((unsigned long long)T << 43)) >> 43;
    T = (T - Y) >> 21;
    long long Z = ((long long)((unsigned long long)T << 42)) >> 42;

    const float inv = 1.0f / QSCALE;
    out[3 * i + 0] = ext[3 * i + 0] + (float)X * inv;
    out[3 * i + 1] = ext[3 * i + 1] + (float)Y * inv;
    out[3 * i + 2] = ext[3 * i + 2] + (float)Z * inv;
}

// ---------------- fallback: fused scan with direct atomic flush -----------
#define NR_FB 8
#define NB_FB 32
#define BLOCK 1024
__global__ __launch_bounds__(BLOCK) void edge_scan_kernel(
    const float* __restrict__ points, const float* __restrict__ force,
    const int* __restrict__ ea, const int* __restrict__ eb,
    float* __restrict__ out,
    int n_edges, int n_points, int range)
{
    extern __shared__ float lds[];
    const int r = blockIdx.x / NB_FB;
    const int c = blockIdx.x % NB_FB;
    const int node0 = r * range;
    const int nwords = range * 3;
    for (int w = threadIdx.x; w < nwords; w += BLOCK) lds[w] = 0.0f;
    __syncthreads();
    const int chunk = (n_edges + NB_FB - 1) / NB_FB;
    const int e0 = c * chunk, e1 = min(n_edges, e0 + chunk);
    for (int e = e0 + (int)threadIdx.x; e < e1; e += BLOCK) {
        int a = ea[e], b = eb[e];
        int la = a - node0, lb = b - node0;
        bool ha = (unsigned)la < (unsigned)range;
        bool hb = (unsigned)lb < (unsigned)range;
        if (!(ha || hb)) continue;
        float ax = points[3*a], ay = points[3*a+1], az = points[3*a+2];
        float bx = points[3*b], by = points[3*b+1], bz = points[3*b+2];
        float vx = bx-ax, vy = by-ay, vz = bz-az;
        float s = -force[e] * rsqrtf(vx*vx+vy*vy+vz*vz);
        float fx = s*vx, fy = s*vy, fz = s*vz;
        if (ha) { atomicAdd(&lds[la*3+0], fx); atomicAdd(&lds[la*3+1], fy); atomicAdd(&lds[la*3+2], fz); }
        if (hb) { atomicAdd(&lds[lb*3+0], -fx); atomicAdd(&lds[lb*3+1], -fy); atomicAdd(&lds[lb*3+2], -fz); }
    }
    __syncthreads();
    const int basew = node0 * 3;
    const int total = n_points * 3;
    for (int w = threadIdx.x; w < nwords; w += BLOCK)
        if (basew + w < total) atomicAdd(&out[basew + w], lds[w]);
}

extern "C" void kernel_launch(void* const* d_in, const int* in_sizes, int n_in,
                              void* d_out, int out_size, void* d_ws, size_t ws_size,
                              hipStream_t stream) {
    const float* points = (const float*)d_in[0];
    const float* ext_f  = (const float*)d_in[1];
    const float* force  = (const float*)d_in[2];
    const int*   ea     = (const int*)d_in[3];
    const int*   eb     = (const int*)d_in[4];
    float* out = (float*)d_out;
    char*  ws  = (char*)d_ws;

    const int n_edges  = in_sizes[2];
    const int total    = out_size;                       // n_points*3
    const int n_points = total / 3;

    const int range5  = (n_points + NR5 - 1) / NR5;      // 20000
    const int np_pad  = range5 * NR5;
    const unsigned magic = (unsigned)((0x100000000ULL + range5 - 1) / (unsigned)range5);
    const int chunk = (((n_edges + NWAVE - 1) / NWAVE) + 3) & ~3;   // x4 aligned

    const size_t lds_consume = (size_t)range5 * sizeof(unsigned long long); // 160000
    const size_t entries_b = (size_t)2 * n_edges * sizeof(uint2);           // 102.4MB
    const size_t partial_b = (size_t)NSLICE * (size_t)np_pad * sizeof(unsigned long long); // 35.2MB
    const size_t cnt_b     = (size_t)NR5 * NWAVE * sizeof(unsigned);        // 80KB
    const size_t tail_need = (2 * cnt_b > partial_b) ? 2 * cnt_b : partial_b;
    const size_t need_new  = entries_b + tail_need + 64;

    const int range_fb = (n_points + NR_FB - 1) / NR_FB;
    const size_t lds_fb = (size_t)range_fb * 3 * sizeof(float);

    hipFuncSetAttribute((const void*)consume_kernel,
                        hipFuncAttributeMaxDynamicSharedMemorySize, (int)lds_consume);
    hipFuncSetAttribute((const void*)edge_scan_kernel,
                        hipFuncAttributeMaxDynamicSharedMemorySize, (int)lds_fb);

    if (range5 <= 0xFFFF && lds_consume <= 160 * 1024 && ws_size >= need_new) {
        uint2*    entries     = (uint2*)ws;
        unsigned long long* partial64 = (unsigned long long*)(ws + entries_b);
        unsigned* counts      = (unsigned*)(ws + entries_b);           // aliases partial64
        unsigned* waveprefix  = counts + (size_t)NR5 * NWAVE;
        unsigned* rangetotals = (unsigned*)(ws + ws_size - 64);        // survives K4

        count_kernel<<<NWAVE / (K1T / 64), K1T, 0, stream>>>(
            ea, eb, counts, n_edges, chunk, magic);
        scan_kernel<<<1, NR5 * 64, 0, stream>>>(counts, waveprefix, rangetotals);
        emit_kernel<<<NBLD3, K3T, 0, stream>>>(
            points, force, ea, eb, waveprefix, rangetotals, entries,
            n_edges, chunk, range5, magic);
        consume_kernel<<<NR5 * NSLICE, K4T, lds_consume, stream>>>(
            (const ushort4*)entries, rangetotals, partial64, np_pad, range5);
        const int rb = 256;
        reduce64_kernel<<<(n_points + rb - 1) / rb, rb, 0, stream>>>(
            ext_f, partial64, out, n_points, np_pad);
    } else {
        hipMemcpyAsync(d_out, (const void*)ext_f, (size_t)total * sizeof(float),
                       hipMemcpyDeviceToDevice, stream);
        edge_scan_kernel<<<NR_FB * NB_FB, BLOCK, lds_fb, stream>>>(
            points, force, ea, eb, out, n_edges, n_points, range_fb);
    }
}